// Round 2
// baseline (622.844 us; speedup 1.0000x reference)
//
#include <hip/hip_runtime.h>
#include <hip/hip_bf16.h>

typedef __attribute__((ext_vector_type(8))) short bf16x8;
typedef __attribute__((ext_vector_type(4))) short bf16x4;
typedef __attribute__((ext_vector_type(4))) float f32x4;

#define NU 20

__device__ __forceinline__ float b2f(unsigned short u) {
    union { float f; unsigned v; } x; x.v = ((unsigned)u) << 16; return x.f;
}
__device__ __forceinline__ unsigned short f2b(float f) {
    union { float f; unsigned v; } x; x.f = f;
    unsigned r = x.v + 0x7FFF + ((x.v >> 16) & 1);
    return (unsigned short)(r >> 16);
}

// ---------------- K0: build WY factors + derived F,G,E,s,bias ----------------
// L = H^U_0...H^U_19 = I - A B^T   (B cols = U rows)
// R = H^V_19...H^V_0 = I - C D^T   (D cols = V rows)
// out = x*s - r.G^T + bias,  r = x.F,  F=[A | S C - A E], G=[S B | D], E=B^T S C
__global__ __launch_bounds__(1024) void k_build(
        const float* __restrict__ U, const float* __restrict__ p,
        const float* __restrict__ V, const float* __restrict__ bias,
        unsigned short* __restrict__ Ft,  // [64][1024] bf16: Ft[c][j] = F[j][c]
        unsigned short* __restrict__ G,   // [1024][64] bf16: G[n][k]
        float* __restrict__ s_ws, float* __restrict__ b_ws) {
    __shared__ float sGU[NU][NU + 1];
    __shared__ float sGV[NU][NU + 1];
    __shared__ float sSig[1024];
    __shared__ float sE[NU][NU + 1];
    __shared__ float sCsc[1024 * 21];  // s_t * c_t[b], stride 21

    const int t = threadIdx.x;
    const int wv = t >> 6, lane = t & 63;

    // P1: sigma = 2R*(sigmoid(p)-0.5)+mean = 0.4*sigmoid(p)+0.6
    float pv = p[t];
    float sig = 0.4f / (1.0f + __expf(-pv)) + 0.6f;
    sSig[t] = sig; s_ws[t] = sig; b_ws[t] = bias[t];

    // P2: Gram matrices (420 dots of length 1024, wave-parallel)
    for (int task = wv; task < 420; task += 16) {
        const float* M = (task < 210) ? U : V;
        int i = (task < 210) ? task : task - 210;
        int k = 0;
        while ((k + 1) * (k + 2) / 2 <= i) k++;
        int j = i - k * (k + 1) / 2;
        const float* rj = M + j * 1024;
        const float* rk = M + k * 1024;
        float acc = 0.0f;
        for (int c = lane; c < 1024; c += 64) acc += rj[c] * rk[c];
        for (int off = 32; off; off >>= 1) acc += __shfl_down(acc, off, 64);
        if (lane == 0) {
            if (task < 210) { sGU[j][k] = acc; sGU[k][j] = acc; }
            else            { sGV[j][k] = acc; sGV[k][j] = acc; }
        }
    }
    __syncthreads();

    // P3: WY recurrences, fully per-thread (t = dim index), no reductions
    float a[NU], c[NU];
    for (int k = 0; k < NU; k++) {            // append order 0..19
        float w = U[k * 1024 + t];
        for (int j = 0; j < k; j++) w -= a[j] * sGU[j][k];
        a[k] = (2.0f / sGU[k][k]) * w;
    }
    for (int k = NU - 1; k >= 0; k--) {       // append order 19..0
        float w = V[k * 1024 + t];
        for (int j = k + 1; j < NU; j++) w -= c[j] * sGV[j][k];
        c[k] = (2.0f / sGV[k][k]) * w;
    }

    // P4: stage s_t*c_t[b] for the E reduction
    for (int b = 0; b < NU; b++) sCsc[t * 21 + b] = sSig[t] * c[b];
    __syncthreads();

    // E[a][b] = sum_t U[a][t] * s_t * C[t][b]   (400 dots, wave-parallel)
    for (int task = wv; task < NU * NU; task += 16) {
        int aa = task / NU, bb = task % NU;
        const float* ra = U + aa * 1024;
        float acc = 0.0f;
        for (int cc = lane; cc < 1024; cc += 64)
            acc += ra[cc] * sCsc[cc * 21 + bb];
        for (int off = 32; off; off >>= 1) acc += __shfl_down(acc, off, 64);
        if (lane == 0) sE[aa][bb] = acc;
    }
    __syncthreads();

    // P5: outputs. Ft rows c: 0..19 = A col, 20..39 = (SC - A E) col, 40..63 = 0
    for (int k = 0; k < NU; k++) Ft[k * 1024 + t] = f2b(a[k]);
    for (int b = 0; b < NU; b++) {
        float v = sSig[t] * c[b];
        for (int al = 0; al < NU; al++) v -= a[al] * sE[al][b];
        Ft[(NU + b) * 1024 + t] = f2b(v);
    }
    for (int k = 2 * NU; k < 64; k++) Ft[k * 1024 + t] = 0;
    // G[n=t][k]: 0..19 = s_t*U[k][t] (S B), 20..39 = V[k-20][t] (D), 40..63 = 0
    for (int k = 0; k < NU; k++) G[t * 64 + k] = f2b(sSig[t] * U[k * 1024 + t]);
    for (int k = 0; k < NU; k++) G[t * 64 + NU + k] = f2b(V[k * 1024 + t]);
    for (int k = 2 * NU; k < 64; k++) G[t * 64 + k] = 0;
}

// ---------------- K1: r(32768x64) = x(32768x1024) . F(1024x64) ----------------
__global__ __launch_bounds__(256) void k_pass1(
        const float* __restrict__ x, const unsigned short* __restrict__ Ft,
        unsigned short* __restrict__ r) {
    __shared__ unsigned short xl[64 * 72];  // [64 rows][64 k] pad 72, bf16
    __shared__ unsigned short fl[64 * 72];  // [64 n][64 k] pad 72, bf16
    const int T = threadIdx.x;
    const int m0 = blockIdx.x * 64;
    const int wv = T >> 6, lane = T & 63;
    const int mc = lane & 15, quad = lane >> 4;

    f32x4 acc[4];
    for (int i = 0; i < 4; i++) acc[i] = (f32x4){0.f, 0.f, 0.f, 0.f};

    for (int k0 = 0; k0 < 1024; k0 += 64) {
        __syncthreads();
        for (int i = 0; i < 4; i++) {   // x tile 64x64 fp32 -> bf16 LDS
            int e = i * 1024 + T * 4;
            int row = e >> 6, col = e & 63;
            f32x4 xv = *(const f32x4*)&x[(size_t)(m0 + row) * 1024 + k0 + col];
            bf16x4 xb;
            for (int j = 0; j < 4; j++) xb[j] = (short)f2b(xv[j]);
            *(bf16x4*)&xl[row * 72 + col] = xb;
        }
        for (int i = 0; i < 2; i++) {   // F^T tile 64x64 (already bf16)
            int e = i * 2048 + T * 8;
            int row = e >> 6, col = e & 63;
            *(bf16x8*)&fl[row * 72 + col] =
                *(const bf16x8*)&Ft[row * 1024 + k0 + col];
        }
        __syncthreads();
        for (int kk = 0; kk < 64; kk += 32) {
            bf16x8 af = *(const bf16x8*)&xl[(wv * 16 + mc) * 72 + kk + quad * 8];
            for (int nt = 0; nt < 4; nt++) {
                bf16x8 bfr = *(const bf16x8*)&fl[(nt * 16 + mc) * 72 + kk + quad * 8];
                acc[nt] = __builtin_amdgcn_mfma_f32_16x16x32_bf16(af, bfr, acc[nt], 0, 0, 0);
            }
        }
    }
    const int rbase = m0 + wv * 16 + quad * 4;
    for (int nt = 0; nt < 4; nt++)
        for (int rg = 0; rg < 4; rg++)
            r[(size_t)(rbase + rg) * 64 + nt * 16 + mc] = f2b(acc[nt][rg]);
}

// -------- K2: out = x*s - r(32768x64).G^T(64x1024) + bias, fused epilogue --------
__global__ __launch_bounds__(256) void k_pass2(
        const float* __restrict__ x, const unsigned short* __restrict__ rr,
        const unsigned short* __restrict__ G, const float* __restrict__ s_ws,
        const float* __restrict__ b_ws, float* __restrict__ out) {
    __shared__ char smem[46080];
    __shared__ float sS[256];
    __shared__ float sB[256];
    unsigned short* rl = (unsigned short*)smem;            // [64][72]
    unsigned short* gl = (unsigned short*)(smem + 9216);   // [256][72]
    unsigned short* ol = (unsigned short*)smem;            // [64][264] (reused)

    const int T = threadIdx.x;
    const int m0 = blockIdx.x * 64;
    const int n0 = blockIdx.y * 256;
    const int wv = T >> 6, lane = T & 63;
    const int mc = lane & 15, quad = lane >> 4;

    sS[T] = s_ws[n0 + T]; sB[T] = b_ws[n0 + T];

    for (int i = 0; i < 2; i++) {  // r tile 64x64 (bf16)
        int e = i * 2048 + T * 8;
        int row = e >> 6, col = e & 63;
        *(bf16x8*)&rl[row * 72 + col] =
            *(const bf16x8*)&rr[(size_t)(m0 + row) * 64 + col];
    }
    for (int i = 0; i < 8; i++) {  // G tile 256x64 (bf16)
        int e = i * 2048 + T * 8;
        int n = e >> 6, k = e & 63;
        *(bf16x8*)&gl[n * 72 + k] = *(const bf16x8*)&G[(size_t)(n0 + n) * 64 + k];
    }
    __syncthreads();

    f32x4 acc[16];
    for (int i = 0; i < 16; i++) acc[i] = (f32x4){0.f, 0.f, 0.f, 0.f};
    for (int kk = 0; kk < 64; kk += 32) {
        bf16x8 af = *(const bf16x8*)&rl[(wv * 16 + mc) * 72 + kk + quad * 8];
        for (int nf = 0; nf < 16; nf++) {
            bf16x8 bfr = *(const bf16x8*)&gl[(nf * 16 + mc) * 72 + kk + quad * 8];
            acc[nf] = __builtin_amdgcn_mfma_f32_16x16x32_bf16(af, bfr, acc[nf], 0, 0, 0);
        }
    }
    __syncthreads();  // done reading rl/gl; reuse as ol

    for (int nf = 0; nf < 16; nf++)
        for (int rg = 0; rg < 4; rg++)
            ol[(wv * 16 + quad * 4 + rg) * 264 + nf * 16 + mc] = f2b(acc[nf][rg]);
    __syncthreads();

    for (int i = 0; i < 8; i++) {  // 64x256 tile epilogue, fp32 x in, fp32 out
        int e = i * 2048 + T * 8;
        int row = e >> 8, col = e & 255;
        bf16x8 av = *(const bf16x8*)&ol[row * 264 + col];
        const float* xp = &x[(size_t)(m0 + row) * 1024 + n0 + col];
        f32x4 x0 = *(const f32x4*)xp;
        f32x4 x1 = *(const f32x4*)(xp + 4);
        f32x4 o0, o1;
        for (int j = 0; j < 4; j++) {
            o0[j] = x0[j] * sS[col + j]     - b2f((unsigned short)av[j])     + sB[col + j];
            o1[j] = x1[j] * sS[col + 4 + j] - b2f((unsigned short)av[4 + j]) + sB[col + 4 + j];
        }
        float* op = &out[(size_t)(m0 + row) * 1024 + n0 + col];
        *(f32x4*)op = o0;
        *(f32x4*)(op + 4) = o1;
    }
}

extern "C" void kernel_launch(void* const* d_in, const int* in_sizes, int n_in,
                              void* d_out, int out_size, void* d_ws, size_t ws_size,
                              hipStream_t stream) {
    const float* x    = (const float*)d_in[0];
    const float* U    = (const float*)d_in[1];
    const float* p    = (const float*)d_in[2];
    const float* V    = (const float*)d_in[3];
    const float* bias = (const float*)d_in[4];

    char* ws = (char*)d_ws;
    unsigned short* Ft = (unsigned short*)ws;               // 131072 B
    unsigned short* G  = (unsigned short*)(ws + 131072);    // 131072 B
    float* s_ws        = (float*)(ws + 262144);             // 4096 B
    float* b_ws        = (float*)(ws + 266240);             // 4096 B
    unsigned short* r  = (unsigned short*)(ws + 270336);    // 4 MiB
    float* out = (float*)d_out;

    hipLaunchKernelGGL(k_build, dim3(1), dim3(1024), 0, stream, U, p, V, bias, Ft, G, s_ws, b_ws);
    hipLaunchKernelGGL(k_pass1, dim3(512), dim3(256), 0, stream, x, Ft, r);
    hipLaunchKernelGGL(k_pass2, dim3(512, 4), dim3(256), 0, stream, x, r, G, s_ws, b_ws, out);
}

// Round 3
// 287.702 us; speedup vs baseline: 2.1649x; 2.1649x over previous
//
#include <hip/hip_runtime.h>
#include <hip/hip_bf16.h>

typedef __attribute__((ext_vector_type(8))) short bf16x8;
typedef __attribute__((ext_vector_type(4))) short bf16x4;
typedef __attribute__((ext_vector_type(4))) float f32x4;

#define NU 20

__device__ __forceinline__ float b2f(unsigned short u) {
    union { float f; unsigned v; } x; x.v = ((unsigned)u) << 16; return x.f;
}
__device__ __forceinline__ unsigned short f2b(float f) {
    union { float f; unsigned v; } x; x.f = f;
    unsigned r = x.v + 0x7FFF + ((x.v >> 16) & 1);
    return (unsigned short)(r >> 16);
}

// ================= build stage (parallelized: 424 + 4 + 400 + 4 blocks) =========
// L = H^U_0...H^U_19 = I - A B^T (B cols = U rows), R = H^V_19...H^V_0 = I - C D^T
// out = x*s - r.G^T + bias,  r = x.F,  F=[A | S C - A E], G=[S B | D], E=B^T S C

// blocks 0..209: GU pair, 210..419: GV pair, 420..423: sigma/bias chunk
__global__ __launch_bounds__(256) void k_gram(
        const float* __restrict__ U, const float* __restrict__ p,
        const float* __restrict__ V, const float* __restrict__ bias,
        float* __restrict__ GU, float* __restrict__ GV,
        float* __restrict__ s_ws, float* __restrict__ b_ws) {
    const int b = blockIdx.x, T = threadIdx.x;
    if (b >= 420) {
        int t = (b - 420) * 256 + T;
        float pv = p[t];
        s_ws[t] = 0.4f / (1.0f + __expf(-pv)) + 0.6f;
        b_ws[t] = bias[t];
        return;
    }
    const float* M = (b < 210) ? U : V;
    float* Gm = (b < 210) ? GU : GV;
    int i = (b < 210) ? b : b - 210;
    int k = 0;
    while ((k + 1) * (k + 2) / 2 <= i) k++;
    int j = i - k * (k + 1) / 2;
    f32x4 a4 = *(const f32x4*)&M[j * 1024 + T * 4];
    f32x4 b4 = *(const f32x4*)&M[k * 1024 + T * 4];
    float acc = a4[0] * b4[0] + a4[1] * b4[1] + a4[2] * b4[2] + a4[3] * b4[3];
    for (int off = 32; off; off >>= 1) acc += __shfl_down(acc, off, 64);
    __shared__ float part[4];
    if ((T & 63) == 0) part[T >> 6] = acc;
    __syncthreads();
    if (T == 0) {
        float s = part[0] + part[1] + part[2] + part[3];
        Gm[j * 20 + k] = s; Gm[k * 20 + j] = s;
    }
}

// 4 blocks x 256: per-dim WY recurrences; writes A, Csc, Ft rows 0..19 & 40..63, G
__global__ __launch_bounds__(256) void k_recur(
        const float* __restrict__ U, const float* __restrict__ V,
        const float* __restrict__ GUg, const float* __restrict__ GVg,
        const float* __restrict__ s_ws,
        float* __restrict__ A, float* __restrict__ Csc,
        unsigned short* __restrict__ Ft, unsigned short* __restrict__ G) {
    __shared__ float sGU[400], sGV[400];
    const int T = threadIdx.x;
    const int t = blockIdx.x * 256 + T;
    for (int i = T; i < 400; i += 256) { sGU[i] = GUg[i]; sGV[i] = GVg[i]; }
    __syncthreads();
    float sig = s_ws[t];
    float a[NU], c[NU];
    for (int k = 0; k < NU; k++) {
        float w = U[k * 1024 + t];
        for (int j = 0; j < k; j++) w -= a[j] * sGU[j * 20 + k];
        a[k] = (2.0f / sGU[k * 20 + k]) * w;
    }
    for (int k = NU - 1; k >= 0; k--) {
        float w = V[k * 1024 + t];
        for (int j = k + 1; j < NU; j++) w -= c[j] * sGV[j * 20 + k];
        c[k] = (2.0f / sGV[k * 20 + k]) * w;
    }
    for (int k = 0; k < NU; k++) { A[k * 1024 + t] = a[k]; Ft[k * 1024 + t] = f2b(a[k]); }
    for (int b = 0; b < NU; b++) Csc[b * 1024 + t] = sig * c[b];
    for (int k = 2 * NU; k < 64; k++) Ft[k * 1024 + t] = 0;
    for (int k = 0; k < NU; k++) G[t * 64 + k] = f2b(sig * U[k * 1024 + t]);
    for (int k = 0; k < NU; k++) G[t * 64 + NU + k] = f2b(V[k * 1024 + t]);
    for (int k = 2 * NU; k < 64; k++) G[t * 64 + k] = 0;
}

// 400 blocks: E[a][b] = dot(U row a, Csc row b)
__global__ __launch_bounds__(256) void k_e(
        const float* __restrict__ U, const float* __restrict__ Csc,
        float* __restrict__ E) {
    const int aa = blockIdx.x / 20, bb = blockIdx.x % 20;
    const int T = threadIdx.x;
    f32x4 a4 = *(const f32x4*)&U[aa * 1024 + T * 4];
    f32x4 b4 = *(const f32x4*)&Csc[bb * 1024 + T * 4];
    float acc = a4[0] * b4[0] + a4[1] * b4[1] + a4[2] * b4[2] + a4[3] * b4[3];
    for (int off = 32; off; off >>= 1) acc += __shfl_down(acc, off, 64);
    __shared__ float part[4];
    if ((T & 63) == 0) part[T >> 6] = acc;
    __syncthreads();
    if (T == 0) E[aa * 20 + bb] = part[0] + part[1] + part[2] + part[3];
}

// 4 blocks x 256: Ft rows 20..39 = (S C - A E) columns
__global__ __launch_bounds__(256) void k_f2(
        const float* __restrict__ A, const float* __restrict__ Csc,
        const float* __restrict__ Eg, unsigned short* __restrict__ Ft) {
    __shared__ float sE[400];
    const int T = threadIdx.x;
    const int t = blockIdx.x * 256 + T;
    for (int i = T; i < 400; i += 256) sE[i] = Eg[i];
    __syncthreads();
    float av[NU];
    for (int a = 0; a < NU; a++) av[a] = A[a * 1024 + t];
    for (int b = 0; b < NU; b++) {
        float v = Csc[b * 1024 + t];
        for (int a = 0; a < NU; a++) v -= av[a] * sE[a * 20 + b];
        Ft[(NU + b) * 1024 + t] = f2b(v);
    }
}

// ============== fused main: r = x.F (Phase A), out = x*s - r.G^T + b (Phase B) ===
// block = 64 rows of x/out. LDS 36864B: [0,18432) xbuf0/xbuf1 (Phase B: gl),
// [18432,27648) fbuf0 (Phase B: rl), [27648,36864) fbuf1.
__global__ __launch_bounds__(256, 2) void k_main(
        const float* __restrict__ x, const unsigned short* __restrict__ Ft,
        const unsigned short* __restrict__ G, const float* __restrict__ s_ws,
        const float* __restrict__ b_ws, float* __restrict__ out) {
    __shared__ __align__(16) char sm[36864];
    unsigned short* xb0 = (unsigned short*)sm;
    unsigned short* xb1 = (unsigned short*)(sm + 9216);
    unsigned short* fb0 = (unsigned short*)(sm + 18432);
    unsigned short* fb1 = (unsigned short*)(sm + 27648);
    unsigned short* rl = fb0;
    unsigned short* gl = (unsigned short*)sm;

    const int T = threadIdx.x;
    const int m0 = blockIdx.x * 64;
    const int wv = T >> 6, lane = T & 63;
    const int mc = lane & 15, quad = lane >> 4;

    // ---- Phase A: r(64x64) = x_tile(64x1024) . F(1024x64), double-buffered ----
    f32x4 acc1[4];
    for (int i = 0; i < 4; i++) acc1[i] = (f32x4){0.f, 0.f, 0.f, 0.f};

#define STAGE_A(k0, xd, fd)                                                     \
    {                                                                           \
        for (int i = 0; i < 4; i++) {                                           \
            int e = i * 1024 + T * 4;                                           \
            int row = e >> 6, col = e & 63;                                     \
            f32x4 xv = *(const f32x4*)&x[(size_t)(m0 + row) * 1024 + (k0) + col];\
            bf16x4 xc;                                                          \
            for (int j = 0; j < 4; j++) xc[j] = (short)f2b(xv[j]);              \
            *(bf16x4*)&(xd)[row * 72 + col] = xc;                               \
        }                                                                       \
        for (int i = 0; i < 2; i++) {                                           \
            int e = i * 2048 + T * 8;                                           \
            int row = e >> 6, col = e & 63;                                     \
            *(bf16x8*)&(fd)[row * 72 + col] =                                   \
                *(const bf16x8*)&Ft[row * 1024 + (k0) + col];                   \
        }                                                                       \
    }

    STAGE_A(0, xb0, fb0);
    for (int kt = 0; kt < 16; kt++) {
        __syncthreads();
        if (kt < 15) {
            if ((kt + 1) & 1) STAGE_A((kt + 1) * 64, xb1, fb1)
            else              STAGE_A((kt + 1) * 64, xb0, fb0)
        }
        const unsigned short* xl = (kt & 1) ? xb1 : xb0;
        const unsigned short* fl = (kt & 1) ? fb1 : fb0;
        for (int kk = 0; kk < 64; kk += 32) {
            bf16x8 af = *(const bf16x8*)&xl[(wv * 16 + mc) * 72 + kk + quad * 8];
            for (int nt = 0; nt < 4; nt++) {
                bf16x8 bfr = *(const bf16x8*)&fl[(nt * 16 + mc) * 72 + kk + quad * 8];
                acc1[nt] = __builtin_amdgcn_mfma_f32_16x16x32_bf16(af, bfr, acc1[nt], 0, 0, 0);
            }
        }
    }
    // r -> LDS (fb0 region: last read at kt=14, fenced by kt=15 top barrier)
    {
        const int rrow = wv * 16 + quad * 4;
        for (int nt = 0; nt < 4; nt++)
            for (int rg = 0; rg < 4; rg++)
                rl[(rrow + rg) * 72 + nt * 16 + mc] = f2b(acc1[nt][rg]);
    }

    // ---- Phase B: out tile = x*s - r.G^T + bias, 8 n-tiles of 128 cols ----
    for (int nt0 = 0; nt0 < 1024; nt0 += 128) {
        __syncthreads();  // prior tile MFMA/phase-A reads done before gl overwrite
        for (int i = 0; i < 4; i++) {  // G[nt0+n][k] -> gl[n*72+k], n<128
            int e = i * 2048 + T * 8;
            int n = e >> 6, k = e & 63;
            *(bf16x8*)&gl[n * 72 + k] = *(const bf16x8*)&G[(size_t)(nt0 + n) * 64 + k];
        }
        __syncthreads();
        f32x4 acc2[8];
        for (int i = 0; i < 8; i++) acc2[i] = (f32x4){0.f, 0.f, 0.f, 0.f};
        for (int kk = 0; kk < 64; kk += 32) {
            bf16x8 af = *(const bf16x8*)&rl[(wv * 16 + mc) * 72 + kk + quad * 8];
            for (int nf = 0; nf < 8; nf++) {
                bf16x8 bfr = *(const bf16x8*)&gl[(nf * 16 + mc) * 72 + kk + quad * 8];
                acc2[nf] = __builtin_amdgcn_mfma_f32_16x16x32_bf16(af, bfr, acc2[nf], 0, 0, 0);
            }
        }
        for (int nf = 0; nf < 8; nf++) {
            int col = nt0 + nf * 16 + mc;
            float sv = s_ws[col], bv = b_ws[col];
            size_t base = (size_t)(m0 + wv * 16 + quad * 4) * 1024 + col;
            out[base]        = x[base]        * sv - acc2[nf][0] + bv;
            out[base + 1024] = x[base + 1024] * sv - acc2[nf][1] + bv;
            out[base + 2048] = x[base + 2048] * sv - acc2[nf][2] + bv;
            out[base + 3072] = x[base + 3072] * sv - acc2[nf][3] + bv;
        }
    }
#undef STAGE_A
}

extern "C" void kernel_launch(void* const* d_in, const int* in_sizes, int n_in,
                              void* d_out, int out_size, void* d_ws, size_t ws_size,
                              hipStream_t stream) {
    const float* x    = (const float*)d_in[0];
    const float* U    = (const float*)d_in[1];
    const float* p    = (const float*)d_in[2];
    const float* V    = (const float*)d_in[3];
    const float* bias = (const float*)d_in[4];

    char* ws = (char*)d_ws;
    unsigned short* Ft = (unsigned short*)ws;               // 131072 B
    unsigned short* G  = (unsigned short*)(ws + 131072);    // 131072 B
    float* s_ws        = (float*)(ws + 262144);             // 4096 B
    float* b_ws        = (float*)(ws + 266240);             // 4096 B
    float* GU          = (float*)(ws + 270336);             // 4096 B
    float* GV          = (float*)(ws + 274432);             // 4096 B
    float* A           = (float*)(ws + 278528);             // 81920 B
    float* Csc         = (float*)(ws + 360448);             // 81920 B
    float* E           = (float*)(ws + 442368);             // 4096 B
    float* out = (float*)d_out;

    hipLaunchKernelGGL(k_gram,  dim3(424), dim3(256), 0, stream, U, p, V, bias, GU, GV, s_ws, b_ws);
    hipLaunchKernelGGL(k_recur, dim3(4),   dim3(256), 0, stream, U, V, GU, GV, s_ws, A, Csc, Ft, G);
    hipLaunchKernelGGL(k_e,     dim3(400), dim3(256), 0, stream, U, Csc, E);
    hipLaunchKernelGGL(k_f2,    dim3(4),   dim3(256), 0, stream, A, Csc, E, Ft);
    hipLaunchKernelGGL(k_main,  dim3(512), dim3(256), 0, stream, x, Ft, G, s_ws, b_ws, out);
}